// Round 1
// 198.514 us; speedup vs baseline: 1.0166x; 1.0166x over previous
//
#include <hip/hip_runtime.h>

// Problem constants (T=512, B=16 -> 8192 tokens), all tensors float32
#define NTOK 8192
#define CDIM 512
#define NB   8
#define RD   64
#define OD   512

// Phase A geometry: 1024 blocks x 128 threads, 8 tokens/block.
// grid 1024 -> 4 blocks/CU -> 8 waves/CU (vs old 256x256 = 1 wave/SIMD).
#define TPB_A 8
#define XPAD  4                    // pad x rows to 516 f32: float4-aligned, conflict-free
#define XROW  (CDIM + XPAD)
#define XROW4 (XROW / 4)

typedef unsigned char u8;

__device__ __forceinline__ float4 f4add(float4 a, float4 b) {
    return make_float4(a.x + b.x, a.y + b.y, a.z + b.z, a.w + b.w);
}

// ---------------------------------------------------------------------------
// Phase A: stage 8 x-rows in LDS; logits with f64 accumulation (sign-critical,
// split across 2 threads per (token,bit), combined via shfl_xor); v = w1 @ x
// with 4 tokens per wave (amortizes w1 L1/L2 reads), identical summation
// order to the previous verified kernel (bitwise-same v).
// ---------------------------------------------------------------------------
__global__ __launch_bounds__(128) void phaseA(
    const float* __restrict__ x, const float* __restrict__ map_w,
    const float* __restrict__ map_b, const float* __restrict__ w1,
    u8* __restrict__ q_out, float* __restrict__ v_out,
    float* __restrict__ loss_out)
{
    const int t    = threadIdx.x;
    const int tok0 = blockIdx.x * TPB_A;
    __shared__ __align__(16) float xs[TPB_A * XROW];   // 16.5 KB

    // ---- stage x tile (coalesced float4 reads, padded LDS rows) ----
    const float4* xsrc = (const float4*)(x + (size_t)tok0 * CDIM);
    #pragma unroll
    for (int i = t; i < TPB_A * (CDIM / 4); i += 128) {
        int r = i >> 7, c = i & 127;                    // CDIM/4 = 128
        *((float4*)(xs + r * XROW) + c) = xsrc[i];
    }
    __syncthreads();

    // ---- logits: (token,bit) pair split over 2 threads (halves of C) ----
    // lane layout within wave: l = g*16 + half*8 + bit  (g = local token 0..3)
    {
        const int bit  = t & 7;
        const int half = (t >> 3) & 1;
        const int tk   = t >> 4;                        // 0..7
        const float4* m4 = (const float4*)(map_w + (size_t)bit * CDIM) + half * 64;
        const float4* x4 = (const float4*)xs + tk * XROW4 + half * 64;
        double a0 = 0.0, a1 = 0.0;
        for (int j = 0; j < 64; ++j) {
            float4 m = m4[j], xv = x4[j];
            a0 += (double)m.x * (double)xv.x + (double)m.y * (double)xv.y;
            a1 += (double)m.z * (double)xv.z + (double)m.w * (double)xv.w;
        }
        double a = a0 + a1;
        a += __shfl_xor(a, 8);                          // combine the two halves
        const double k = a + (double)map_b[bit];
        const unsigned long long m = __ballot(k > 0.0);
        if ((t & 15) == 0) {
            int g = (t >> 4) & 3;                       // local token in wave
            q_out[tok0 + tk] = (u8)((m >> (g * 16)) & 0xFFull);
        }
    }

    // ---- v: wave tg -> tokens tg*4..tg*4+3, lane r = w1 row ----
    {
        const int r  = t & 63;
        const int tg = t >> 6;                          // 0..1
        const float4* w4 = (const float4*)(w1 + (size_t)r * CDIM);
        const float4* xb = (const float4*)xs + (size_t)(tg * 4) * XROW4;
        float acc0 = 0.f, acc1 = 0.f, acc2 = 0.f, acc3 = 0.f;
        for (int j = 0; j < CDIM / 4; ++j) {
            float4 wv = w4[j];
            float4 x0 = xb[j];
            float4 x1 = xb[XROW4 + j];
            float4 x2 = xb[2 * XROW4 + j];
            float4 x3 = xb[3 * XROW4 + j];
            acc0 += wv.x * x0.x + wv.y * x0.y + wv.z * x0.z + wv.w * x0.w;
            acc1 += wv.x * x1.x + wv.y * x1.y + wv.z * x1.z + wv.w * x1.w;
            acc2 += wv.x * x2.x + wv.y * x2.y + wv.z * x2.z + wv.w * x2.w;
            acc3 += wv.x * x3.x + wv.y * x3.y + wv.z * x3.z + wv.w * x3.w;
        }
        float* vo = v_out + (size_t)(tok0 + tg * 4) * RD + r;   // coalesced
        vo[0 * RD] = acc0; vo[1 * RD] = acc1; vo[2 * RD] = acc2; vo[3 * RD] = acc3;
    }

    if (blockIdx.x == 0 && t == 0) loss_out[0] = 0.0f;  // loss = 0
}

// ---------------------------------------------------------------------------
// Phase B: 4 blocks per code (grid 1024 x 128 thr) -> 4 blocks/CU so weight
// bursts of one block overlap compute of another. Each thread owns output
// o = quarter*128 + t; its fused weight row w21[q,o,:]+w22[255-q,o,:] lives
// in 16 NAMED float4 registers (the old float w[64] array spilled to scratch:
// VGPR_Count was 52 < 64). Weight loads are issued before the token scan so
// they are in flight during it.
// ---------------------------------------------------------------------------
__global__ __launch_bounds__(128) void phaseB(
    const u8* __restrict__ q_arr, const float* __restrict__ v_arr,
    const float* __restrict__ w21, const float* __restrict__ w22,
    const float* __restrict__ pwB, float* __restrict__ y)
{
    const int q  = blockIdx.x >> 2;
    const int qu = blockIdx.x & 3;
    const int t  = threadIdx.x;
    const int o  = qu * 128 + t;

    __shared__ unsigned short list[NTOK];   // 16 KB (worst case: all tokens one code)
    __shared__ int cnt;
    __shared__ __align__(16) float vs[8 * RD];  // 2 KB

    // ---- issue fused-weight loads first (32 independent float4 loads) ----
    const float4* pa = (const float4*)w21 + (size_t)q * (OD * RD / 4) + (size_t)o * (RD / 4);
    const float4* pb = (const float4*)w22 + (size_t)(255 - q) * (OD * RD / 4) + (size_t)o * (RD / 4);
    float4 a0 = pa[0],  a1 = pa[1],  a2 = pa[2],  a3 = pa[3],
           a4 = pa[4],  a5 = pa[5],  a6 = pa[6],  a7 = pa[7],
           a8 = pa[8],  a9 = pa[9],  a10 = pa[10], a11 = pa[11],
           a12 = pa[12], a13 = pa[13], a14 = pa[14], a15 = pa[15];
    float4 b0 = pb[0],  b1 = pb[1],  b2 = pb[2],  b3 = pb[3],
           b4 = pb[4],  b5 = pb[5],  b6 = pb[6],  b7 = pb[7],
           b8 = pb[8],  b9 = pb[9],  b10 = pb[10], b11 = pb[11],
           b12 = pb[12], b13 = pb[13], b14 = pb[14], b15 = pb[15];

    if (t == 0) cnt = 0;
    __syncthreads();

    // ---- build token list for this code (uint4 scan, LDS atomic append) ----
    const uint4* qa = (const uint4*)q_arr;
    for (int i = t; i < NTOK / 16; i += 128) {
        uint4 u = qa[i];
        int sbase = i * 16;
#define CHK(WORD, OFF) { unsigned uw = (WORD); \
        if ((int)(uw & 0xFFu)         == q) list[atomicAdd(&cnt, 1)] = (unsigned short)(sbase + (OFF));     \
        if ((int)((uw >> 8)  & 0xFFu) == q) list[atomicAdd(&cnt, 1)] = (unsigned short)(sbase + (OFF) + 1); \
        if ((int)((uw >> 16) & 0xFFu) == q) list[atomicAdd(&cnt, 1)] = (unsigned short)(sbase + (OFF) + 2); \
        if ((int)(uw >> 24)           == q) list[atomicAdd(&cnt, 1)] = (unsigned short)(sbase + (OFF) + 3); }
        CHK(u.x, 0) CHK(u.y, 4) CHK(u.z, 8) CHK(u.w, 12)
#undef CHK
    }
    __syncthreads();
    const int n = cnt;
    if (n == 0) return;                                 // uniform exit, no later syncs

    // ---- combine fused weights into 16 named registers ----
    float4 w0 = f4add(a0, b0),  w1 = f4add(a1, b1),  w2 = f4add(a2, b2),  w3 = f4add(a3, b3),
           w4 = f4add(a4, b4),  w5 = f4add(a5, b5),  w6 = f4add(a6, b6),  w7 = f4add(a7, b7),
           w8 = f4add(a8, b8),  w9 = f4add(a9, b9),  w10 = f4add(a10, b10), w11 = f4add(a11, b11),
           w12 = f4add(a12, b12), w13 = f4add(a13, b13), w14 = f4add(a14, b14), w15 = f4add(a15, b15);
    const float bias = pwB[o];

    // ---- stream tokens in batches of 8, compute pairs for 2 acc chains ----
    const float4* v4 = (const float4*)v_arr;
    for (int base = 0; base < n; base += 8) {
        const int nb = min(8, n - base);
        if (t < nb * 16)                                // 8 tok x 16 float4 = 128 loads
            ((float4*)vs)[t] = v4[(size_t)list[base + (t >> 4)] * (RD / 4) + (t & 15)];
        __syncthreads();
        int i = 0;
        for (; i + 2 <= nb; i += 2) {
            const float4* p0 = (const float4*)vs + (size_t)i * 16;
            const float4* p1 = p0 + 16;
            float acc0 = bias, acc1 = bias;
#define STEP(J, W) { float4 u0 = p0[J], u1 = p1[J]; \
            acc0 += W.x * u0.x + W.y * u0.y + W.z * u0.z + W.w * u0.w; \
            acc1 += W.x * u1.x + W.y * u1.y + W.z * u1.z + W.w * u1.w; }
            STEP(0, w0)  STEP(1, w1)  STEP(2, w2)  STEP(3, w3)
            STEP(4, w4)  STEP(5, w5)  STEP(6, w6)  STEP(7, w7)
            STEP(8, w8)  STEP(9, w9)  STEP(10, w10) STEP(11, w11)
            STEP(12, w12) STEP(13, w13) STEP(14, w14) STEP(15, w15)
#undef STEP
            y[(size_t)list[base + i]     * OD + o] = acc0;
            y[(size_t)list[base + i + 1] * OD + o] = acc1;
        }
        if (i < nb) {                                   // odd tail
            const float4* p0 = (const float4*)vs + (size_t)i * 16;
            float acc0 = bias;
#define STEP1(J, W) { float4 u0 = p0[J]; \
            acc0 += W.x * u0.x + W.y * u0.y + W.z * u0.z + W.w * u0.w; }
            STEP1(0, w0)  STEP1(1, w1)  STEP1(2, w2)  STEP1(3, w3)
            STEP1(4, w4)  STEP1(5, w5)  STEP1(6, w6)  STEP1(7, w7)
            STEP1(8, w8)  STEP1(9, w9)  STEP1(10, w10) STEP1(11, w11)
            STEP1(12, w12) STEP1(13, w13) STEP1(14, w14) STEP1(15, w15)
#undef STEP1
            y[(size_t)list[base + i] * OD + o] = acc0;
        }
        __syncthreads();
    }
}

// ---------------------------------------------------------------------------
// Fallback (ws too small): workspace-free, one block per token.
// ---------------------------------------------------------------------------
__global__ __launch_bounds__(256) void mono(
    const float* __restrict__ x, const float* __restrict__ map_w,
    const float* __restrict__ map_b, const float* __restrict__ w1,
    const float* __restrict__ w21, const float* __restrict__ w22,
    const float* __restrict__ pwB, float* __restrict__ y)
{
    const int tok = blockIdx.x;
    const int t   = threadIdx.x;
    __shared__ float xsh[CDIM];
    __shared__ float vsh[RD];
    __shared__ int qsh;

    if (t == 0) qsh = 0;
    for (int i = t; i < CDIM; i += 256) xsh[i] = x[(size_t)tok * CDIM + i];
    __syncthreads();

    if (t < NB) {
        double a = 0.0;
        const float* mrow = map_w + (size_t)t * CDIM;
        for (int j = 0; j < CDIM; ++j) a += (double)mrow[j] * (double)xsh[j];
        a += (double)map_b[t];
        if (a > 0.0) atomicOr(&qsh, 1 << t);
    }
    if (t < RD) {
        const float* wrow = w1 + (size_t)t * CDIM;
        float acc = 0.f;
        for (int j = 0; j < CDIM; ++j) acc += wrow[j] * xsh[j];
        vsh[t] = acc;
    }
    __syncthreads();

    const int q = qsh;
    for (int o = t; o < OD; o += 256) {
        const float* pa = w21 + (size_t)q * (OD * RD) + (size_t)o * RD;
        const float* pb = w22 + (size_t)(255 - q) * (OD * RD) + (size_t)o * RD;
        float acc = pwB[o];
        for (int r = 0; r < RD; ++r) acc += (pa[r] + pb[r]) * vsh[r];
        y[(size_t)tok * OD + o] = acc;
    }
    if (tok == 0 && t == 0) y[(size_t)NTOK * OD] = 0.0f;
}

extern "C" void kernel_launch(void* const* d_in, const int* in_sizes, int n_in,
                              void* d_out, int out_size, void* d_ws, size_t ws_size,
                              hipStream_t stream) {
    const float* x     = (const float*)d_in[0];
    // d_in[1] = key: unused by the forward pass
    const float* map_w = (const float*)d_in[2];
    const float* map_b = (const float*)d_in[3];
    const float* w1    = (const float*)d_in[4];
    const float* w21   = (const float*)d_in[5];
    const float* w22   = (const float*)d_in[6];
    const float* pwB   = (const float*)d_in[7];
    float* out = (float*)d_out;

    const size_t need = (size_t)NTOK + (size_t)NTOK * RD * sizeof(float); // 8KB + 2MB
    if (ws_size >= need) {
        u8*    q_ws = (u8*)d_ws;
        float* v_ws = (float*)((char*)d_ws + NTOK);
        phaseA<<<NTOK / TPB_A, 128, 0, stream>>>(x, map_w, map_b, w1, q_ws, v_ws,
                                                 out + (size_t)NTOK * OD);
        phaseB<<<256 * 4, 128, 0, stream>>>(q_ws, v_ws, w21, w22, pwB, out);
    } else {
        mono<<<NTOK, 256, 0, stream>>>(x, map_w, map_b, w1, w21, w22, pwB, out);
    }
}